// Round 6
// baseline (342.843 us; speedup 1.0000x reference)
//
#include <hip/hip_runtime.h>

// BERT-CRF fused. Shapes: B=64, S=512, E=1024, T=9.
// d_out: [0]=llh, [1 .. 1+B*S*T)=emission (B,S,T) fp32.
//
// emis_kernel (row-per-lane, reduction-free): block = 1 wave = 64 rows, 512
//   blocks (2 waves/CU). Each lane owns a full row: 9 serial 1024-dots
//   (9216 v_fma, SIMD issue floor 18.4k cyc = 7.7 us). W is indexed with
//   thread-independent (uniform) indices -> compiler emits s_load: W rides
//   the scalar pipe/K$, costing ZERO VMEM/DS ops. x is staged per 32-elem
//   chunk through LDS (coalesced global dwordx4 in, odd-stride-33 rows ->
//   2-way-free bank access out), double-buffered, next chunk prefetched.
//   No shuffles, no barriers (single wave). Kills the 54-shuffle/row DS cost
//   that pinned R3-R5 emis at ~60 us.
//
// CRF scan in LINEAR space: em is log_softmax so exp(em) rows sum to 1;
// transfer matrices M_s = exp(trans) o diag(exp(em_s)) have row sums
// ~e^{+-0.1}; 511-step products stay fp32-safe, no rescaling, no LSE chain.
//   crf_chunk: 4096 waves (64 b x 64 chunks of 8 steps), 9x9 product in regs,
//     masked steps = identity. Writes matrices to d_ws (4096*81*4 = 1.33 MB).
//   crf_final: 64 blocks x 256: numerator + LDS tree reduction (depth 6,
//     append-buffer), den = log(v0^T Mtot e^end), atomicAdd into out[0]
//     (zeroed by emis block 0 each call).

#define BB 64
#define SS 512
#define EE 1024
#define TT 9

#define XCH 32                 // chunk of E per stage
#define XSTRIDE 33             // odd dword stride: bank = (lane + e) % 32, 2-way free

__global__ __launch_bounds__(64) void emis_kernel(
    const float* __restrict__ embed,   // (B*S, E)
    const float* __restrict__ W,       // (T, E)
    const float* __restrict__ bias,    // (T)
    float* __restrict__ out)           // [0]=llh, [1..]=emission
{
    __shared__ float xs[2][64 * XSTRIDE];   // 2 x 8.25 KB

    const int lane = threadIdx.x;
    const int row0 = blockIdx.x * 64;

    if (blockIdx.x == 0 && lane == 0) out[0] = 0.0f;  // llh accumulator

    const int lr = lane >> 3;      // row sub-index for staging (8 rows / instr)
    const int le = lane & 7;       // float4 index within 32-float chunk

    // acc[t] starts at bias[t] (uniform s_load)
    float acc[TT];
#pragma unroll
    for (int t = 0; t < TT; ++t) acc[t] = bias[t];

    // prologue: load chunk 0 (8 instrs, each = 8 rows x 128 B coalesced)
    float4 ld[8];
#pragma unroll
    for (int k = 0; k < 8; ++k)
        ld[k] = *(const float4*)(embed + (size_t)(row0 + 8 * k + lr) * EE + 4 * le);

    for (int c = 0; c < EE / XCH; ++c) {
        float* buf = xs[c & 1];

        // stage held regs -> LDS (odd stride; 2-way bank aliasing = free)
#pragma unroll
        for (int k = 0; k < 8; ++k) {
            float* p = buf + (8 * k + lr) * XSTRIDE + 4 * le;
            p[0] = ld[k].x; p[1] = ld[k].y; p[2] = ld[k].z; p[3] = ld[k].w;
        }

        // prefetch next chunk while computing this one
        if (c + 1 < EE / XCH) {
#pragma unroll
            for (int k = 0; k < 8; ++k)
                ld[k] = *(const float4*)(embed +
                        (size_t)(row0 + 8 * k + lr) * EE + (c + 1) * XCH + 4 * le);
        }

        // my row's chunk into VGPRs (bank-conflict-free b32 reads)
        float xv[XCH];
#pragma unroll
        for (int e = 0; e < XCH; ++e)
            xv[e] = buf[lane * XSTRIDE + e];

        // 9 x 32 FMA; W index is uniform (no threadIdx) -> s_load + v_fmac(v,s,v)
#pragma unroll
        for (int t = 0; t < TT; ++t) {
            const float* wrow = W + t * EE + c * XCH;
#pragma unroll
            for (int e = 0; e < XCH; ++e)
                acc[t] += xv[e] * wrow[e];
        }
    }

    // per-lane log_softmax over T=9 (no cross-lane ops at all)
    float mx = acc[0];
#pragma unroll
    for (int t = 1; t < TT; ++t) mx = fmaxf(mx, acc[t]);
    float ssum = 0.0f;
#pragma unroll
    for (int t = 0; t < TT; ++t) ssum += __expf(acc[t] - mx);
    const float lse = mx + __logf(ssum);

    // 9 consecutive floats per lane -> compiler merges into dwordx4 stores
    float* orow = out + 1 + (size_t)(row0 + lane) * TT;
#pragma unroll
    for (int t = 0; t < TT; ++t)
        orow[t] = acc[t] - lse;
}

// ---- CRF stage 1: per-chunk linear-space matrix products ----
__global__ __launch_bounds__(256) void crf_chunk(
    const float* __restrict__ outbase,  // d_out ([0]=llh, em at +1)
    const int* __restrict__ mask,       // (B,S)
    const float* __restrict__ trans,    // (T,T)
    float* __restrict__ ws)             // (B*64) matrices of 81 floats
{
    const int gw   = (blockIdx.x * 256 + threadIdx.x) >> 6;  // 0..4095
    const int lane = threadIdx.x & 63;
    const int b = gw >> 6;        // batch
    const int c = gw & 63;        // chunk
    const int i = (lane < TT) ? lane : 0;  // row of chunk product

    const float* em = outbase + 1 + (size_t)b * SS * TT;

    // E = exp(trans): lane-uniform, 81 VGPRs
    float E[TT * TT];
#pragma unroll
    for (int e = 0; e < TT * TT; ++e) E[e] = __expf(trans[e]);

    // first step of this chunk: s0 = 8c+1
    const int s0 = 8 * c + 1;
    float R[TT];
    {
        float p[TT];
#pragma unroll
        for (int j = 0; j < TT; ++j) p[j] = __expf(em[s0 * TT + j]);
        const int mk = mask[b * SS + s0];
#pragma unroll
        for (int k = 0; k < TT; ++k)
            R[k] = mk ? (E[i * TT + k] * p[k]) : ((k == i) ? 1.0f : 0.0f);
    }
#pragma unroll
    for (int d = 1; d < 8; ++d) {
        const int s = s0 + d;
        const bool valid = (s < SS);          // chunk 63 has only 7 steps
        const int sc = valid ? s : (SS - 1);
        float p[TT];
#pragma unroll
        for (int j = 0; j < TT; ++j) p[j] = __expf(em[sc * TT + j]);
        const int mk = valid ? mask[b * SS + sc] : 0;  // invalid/masked -> identity

        float nR[TT];
#pragma unroll
        for (int j = 0; j < TT; ++j) {
            float a = 0.0f;
#pragma unroll
            for (int k = 0; k < TT; ++k) a += R[k] * E[k * TT + j];
            nR[j] = a * p[j];
        }
#pragma unroll
        for (int j = 0; j < TT; ++j) R[j] = mk ? nR[j] : R[j];
    }
    if (lane < TT) {
#pragma unroll
        for (int j = 0; j < TT; ++j)
            ws[(size_t)gw * 81 + i * TT + j] = R[j];
    }
}

// ---- CRF stage 2: per-batch tree reduction + numerator + llh ----
__global__ __launch_bounds__(256) void crf_final(
    const float* __restrict__ outbase,
    const int* __restrict__ tags,
    const int* __restrict__ mask,
    const float* __restrict__ start_t,
    const float* __restrict__ end_t,
    const float* __restrict__ trans,
    const float* __restrict__ ws,
    float* __restrict__ out)
{
    __shared__ float mats[127 * 81];   // 64 in + 32+16+8+4+2+1 level outputs
    __shared__ float red[4];
    __shared__ float redm[4];

    const int b = blockIdx.x;
    const int tid = threadIdx.x;
    const int lane = tid & 63, wid = tid >> 6;
    const float* em = outbase + 1 + (size_t)b * SS * TT;

    for (int idx = tid; idx < 64 * 81; idx += 256)
        mats[idx] = ws[(size_t)b * 64 * 81 + idx];

    // ---- numerator: threads cover s = tid, tid+256 ----
    float num = 0.0f;
    int msum = 0;
    for (int s = tid; s < SS; s += 256) {
        const int mk = mask[b * SS + s];
        msum += mk;
        const int tg = tags[b * SS + s];
        if (s == 0) {
            num += start_t[tg] + em[tg];
        } else {
            const int tp = tags[b * SS + s - 1];
            num += (float)mk * (trans[tp * TT + tg] + em[s * TT + tg]);
        }
    }
#pragma unroll
    for (int o = 32; o > 0; o >>= 1) {
        num += __shfl_xor(num, o, 64);
        msum += __shfl_xor(msum, o, 64);
    }
    if (lane == 0) { red[wid] = num; redm[wid] = (float)msum; }
    __syncthreads();

    // ---- tree reduction: levels n = 32,16,8,4,2,1, append-buffer ----
    int inOff = 0, outOff = 64;
    for (int n = 32; n >= 1; n >>= 1) {
        for (int c = wid; c < n; c += 4) {
            const float* A  = mats + (inOff + 2 * c) * 81;
            const float* Bm = mats + (inOff + 2 * c + 1) * 81;
            float* C = mats + (outOff + c) * 81;
            int e = lane;                       // entries 0..63
            int ii = e / 9, jj = e - ii * 9;
            float a = 0.0f;
#pragma unroll
            for (int k = 0; k < TT; ++k) a += A[ii * 9 + k] * Bm[k * 9 + jj];
            C[e] = a;
            if (lane < 17) {                    // entries 64..80
                e = 64 + lane; ii = e / 9; jj = e - ii * 9;
                float a2 = 0.0f;
#pragma unroll
                for (int k = 0; k < TT; ++k) a2 += A[ii * 9 + k] * Bm[k * 9 + jj];
                C[e] = a2;
            }
        }
        __syncthreads();
        inOff = outOff; outOff += n;
    }
    // Mtot at mats + 126*81

    if (wid == 0) {
        const float* Mt = mats + 126 * 81;
        float v0[TT];
#pragma unroll
        for (int i2 = 0; i2 < TT; ++i2) v0[i2] = __expf(start_t[i2] + em[i2]);
        const int j = (lane < TT) ? lane : 0;
        float cs = 0.0f;
#pragma unroll
        for (int i2 = 0; i2 < TT; ++i2) cs += v0[i2] * Mt[i2 * 9 + j];
        float val = cs * __expf(end_t[j]);
        if (lane >= TT) val = 0.0f;
        // sum lanes 0..8 (lanes 9..15 are zero) via width-16 butterfly
#pragma unroll
        for (int o = 8; o > 0; o >>= 1) val += __shfl_xor(val, o, 64);
        if (lane == 0) {
            const float den = __logf(val);
            float numT = red[0] + red[1] + red[2] + red[3];
            const int ms = (int)(redm[0] + redm[1] + redm[2] + redm[3]);
            numT += end_t[tags[b * SS + (ms - 1)]];
            atomicAdd(out, numT - den);
        }
    }
}

extern "C" void kernel_launch(void* const* d_in, const int* in_sizes, int n_in,
                              void* d_out, int out_size, void* d_ws, size_t ws_size,
                              hipStream_t stream) {
    const float* embed   = (const float*)d_in[0];
    const int*   tags    = (const int*)d_in[1];
    const int*   mask    = (const int*)d_in[2];
    const float* W       = (const float*)d_in[3];
    const float* bias    = (const float*)d_in[4];
    const float* start_t = (const float*)d_in[5];
    const float* end_t   = (const float*)d_in[6];
    const float* trans   = (const float*)d_in[7];
    float* out = (float*)d_out;
    float* ws  = (float*)d_ws;   // needs 4096*81*4 = 1.33 MB

    // 32768 rows, 64 rows per single-wave block
    emis_kernel<<<512, 64, 0, stream>>>(embed, W, bias, out);
    // 4096 chunk-waves / 4 waves per block
    crf_chunk<<<1024, 256, 0, stream>>>(out, mask, trans, ws);
    // one block per batch
    crf_final<<<BB, 256, 0, stream>>>(out, tags, mask, start_t, end_t, trans, ws, out);
}

// Round 7
// 259.411 us; speedup vs baseline: 1.3216x; 1.3216x over previous
//
#include <hip/hip_runtime.h>

// BERT-CRF fused. Shapes: B=64, S=512, E=1024, T=9.
// d_out: [0]=llh, [1 .. 1+B*S*T)=emission (B,S,T) fp32.
//
// emis_kernel (MFMA bf16): tag_space = embed(32768x1024) @ W^T(1024x9) done
//   on the matrix cores. Per block (256 thr, 4 waves): W converted fp32->bf16
//   once into LDS (16 rows x stride-1032, rows 9..15 zero); each wave owns a
//   16x16 output tile (M=16 rows, N=16 cols, 9 used), K-loop 32 steps of
//   mfma_f32_16x16x32_bf16. A-frag loaded straight from global (2 dwordx4 /
//   lane / step) + RNE pack to bf16; B-frag = 1 ds_read_b128 / step.
//   Epilogue: C-frag -> small LDS tile -> per-row log_softmax (+bias) ->
//   9-float contiguous store. Zero wave-wide shuffles (R2-R5 paid ~54
//   DS-shuffles/row); one barrier per block. bf16 input rounding adds ~5e-3
//   abs error on emission - well inside threshold.
//
// CRF scan in LINEAR space: em is log_softmax so exp(em) rows sum to 1;
// transfer matrices M_s = exp(trans) o diag(exp(em_s)) have row sums
// ~e^{+-0.1}; 511-step products stay fp32-safe, no rescaling, no LSE chain.
//   crf_chunk: 4096 waves (64 b x 64 chunks of 8 steps), 9x9 product in regs.
//   crf_final: 64 blocks x 256: numerator + LDS tree reduction, den =
//     log(v0^T Mtot e^end), atomicAdd into out[0] (zeroed by emis block 0).

#define BB 64
#define SS 512
#define EE 1024
#define TT 9

typedef __attribute__((ext_vector_type(8))) short bf16x8;
typedef __attribute__((ext_vector_type(4))) float f32x4;

#define WSTR 1032   // bf16 elements per padded W row in LDS

__device__ __forceinline__ short f2bf(float f) {
    union { float f; unsigned u; } v; v.f = f;
    return (short)((v.u + 0x7FFFu + ((v.u >> 16) & 1u)) >> 16);  // RNE
}

__global__ __launch_bounds__(256) void emis_kernel(
    const float* __restrict__ embed,   // (B*S, E)
    const float* __restrict__ W,       // (T, E)
    const float* __restrict__ bias,    // (T)
    float* __restrict__ out)           // [0]=llh, [1..]=emission
{
    __shared__ short Wb[16 * WSTR];        // 33 KB bf16 W, rows 9..15 zero
    __shared__ float tile[4][16][17];      // per-wave epilogue tile

    const int tid  = threadIdx.x;
    const int wv   = tid >> 6;
    const int lane = tid & 63;

    if (blockIdx.x == 0 && tid == 0) out[0] = 0.0f;  // llh accumulator

    // zero Wb (as dwords), then fill rows 0..8 with bf16(W)
    {
        unsigned* wz = (unsigned*)Wb;
        for (int i = tid; i < (16 * WSTR) / 2; i += 256) wz[i] = 0u;
    }
    __syncthreads();
    for (int idx = tid; idx < TT * EE; idx += 256) {
        const int t = idx >> 10, k = idx & 1023;
        Wb[t * WSTR + k] = f2bf(W[idx]);
    }
    __syncthreads();

    const int q   = lane >> 4;      // quad 0..3
    const int mn  = lane & 15;      // row (A/C) or col (B)
    const int row = blockIdx.x * 64 + wv * 16 + mn;   // this lane's A row

    // B-frag base: lane needs Wb[n=mn][k = 32*it + 8*q .. +8)
    const short* bptr = Wb + mn * WSTR + 8 * q;
    const float* arow = embed + (size_t)row * EE + 8 * q;

    f32x4 acc = {0.f, 0.f, 0.f, 0.f};

    float4 a0 = *(const float4*)(arow);
    float4 a1 = *(const float4*)(arow + 4);

    for (int it = 0; it < 32; ++it) {
        // pack current A chunk to bf16
        bf16x8 afrag;
        afrag[0] = f2bf(a0.x); afrag[1] = f2bf(a0.y);
        afrag[2] = f2bf(a0.z); afrag[3] = f2bf(a0.w);
        afrag[4] = f2bf(a1.x); afrag[5] = f2bf(a1.y);
        afrag[6] = f2bf(a1.z); afrag[7] = f2bf(a1.w);

        // prefetch next A chunk
        if (it + 1 < 32) {
            a0 = *(const float4*)(arow + (it + 1) * 32);
            a1 = *(const float4*)(arow + (it + 1) * 32 + 4);
        }

        const bf16x8 bfrag = *(const bf16x8*)(bptr + it * 32);  // ds_read_b128

        acc = __builtin_amdgcn_mfma_f32_16x16x32_bf16(afrag, bfrag, acc, 0, 0, 0);
    }

    // C layout: col = lane&15, row_in_tile = 4*q + reg  (m89-verified)
#pragma unroll
    for (int r = 0; r < 4; ++r)
        tile[wv][4 * q + r][mn] = acc[r];
    // same-wave LDS RAW: compiler inserts lgkmcnt wait; no barrier needed.

    if (lane < 16) {
        float v[TT];
        float mx = -1e30f;
#pragma unroll
        for (int t = 0; t < TT; ++t) {
            v[t] = tile[wv][lane][t] + bias[t];
            mx = fmaxf(mx, v[t]);
        }
        float ssum = 0.0f;
#pragma unroll
        for (int t = 0; t < TT; ++t) ssum += __expf(v[t] - mx);
        const float lse = mx + __logf(ssum);

        float* orow = out + 1 + (size_t)(blockIdx.x * 64 + wv * 16 + lane) * TT;
#pragma unroll
        for (int t = 0; t < TT; ++t)
            orow[t] = v[t] - lse;
    }
}

// ---- CRF stage 1: per-chunk linear-space matrix products ----
__global__ __launch_bounds__(256) void crf_chunk(
    const float* __restrict__ outbase,  // d_out ([0]=llh, em at +1)
    const int* __restrict__ mask,       // (B,S)
    const float* __restrict__ trans,    // (T,T)
    float* __restrict__ ws)             // (B*64) matrices of 81 floats
{
    const int gw   = (blockIdx.x * 256 + threadIdx.x) >> 6;  // 0..4095
    const int lane = threadIdx.x & 63;
    const int b = gw >> 6;        // batch
    const int c = gw & 63;        // chunk
    const int i = (lane < TT) ? lane : 0;  // row of chunk product

    const float* em = outbase + 1 + (size_t)b * SS * TT;

    // E = exp(trans): lane-uniform, 81 VGPRs
    float E[TT * TT];
#pragma unroll
    for (int e = 0; e < TT * TT; ++e) E[e] = __expf(trans[e]);

    // first step of this chunk: s0 = 8c+1
    const int s0 = 8 * c + 1;
    float R[TT];
    {
        float p[TT];
#pragma unroll
        for (int j = 0; j < TT; ++j) p[j] = __expf(em[s0 * TT + j]);
        const int mk = mask[b * SS + s0];
#pragma unroll
        for (int k = 0; k < TT; ++k)
            R[k] = mk ? (E[i * TT + k] * p[k]) : ((k == i) ? 1.0f : 0.0f);
    }
#pragma unroll
    for (int d = 1; d < 8; ++d) {
        const int s = s0 + d;
        const bool valid = (s < SS);          // chunk 63 has only 7 steps
        const int sc = valid ? s : (SS - 1);
        float p[TT];
#pragma unroll
        for (int j = 0; j < TT; ++j) p[j] = __expf(em[sc * TT + j]);
        const int mk = valid ? mask[b * SS + sc] : 0;  // invalid/masked -> identity

        float nR[TT];
#pragma unroll
        for (int j = 0; j < TT; ++j) {
            float a = 0.0f;
#pragma unroll
            for (int k = 0; k < TT; ++k) a += R[k] * E[k * TT + j];
            nR[j] = a * p[j];
        }
#pragma unroll
        for (int j = 0; j < TT; ++j) R[j] = mk ? nR[j] : R[j];
    }
    if (lane < TT) {
#pragma unroll
        for (int j = 0; j < TT; ++j)
            ws[(size_t)gw * 81 + i * TT + j] = R[j];
    }
}

// ---- CRF stage 2: per-batch tree reduction + numerator + llh ----
__global__ __launch_bounds__(256) void crf_final(
    const float* __restrict__ outbase,
    const int* __restrict__ tags,
    const int* __restrict__ mask,
    const float* __restrict__ start_t,
    const float* __restrict__ end_t,
    const float* __restrict__ trans,
    const float* __restrict__ ws,
    float* __restrict__ out)
{
    __shared__ float mats[127 * 81];   // 64 in + 32+16+8+4+2+1 level outputs
    __shared__ float red[4];
    __shared__ float redm[4];

    const int b = blockIdx.x;
    const int tid = threadIdx.x;
    const int lane = tid & 63, wid = tid >> 6;
    const float* em = outbase + 1 + (size_t)b * SS * TT;

    for (int idx = tid; idx < 64 * 81; idx += 256)
        mats[idx] = ws[(size_t)b * 64 * 81 + idx];

    // ---- numerator: threads cover s = tid, tid+256 ----
    float num = 0.0f;
    int msum = 0;
    for (int s = tid; s < SS; s += 256) {
        const int mk = mask[b * SS + s];
        msum += mk;
        const int tg = tags[b * SS + s];
        if (s == 0) {
            num += start_t[tg] + em[tg];
        } else {
            const int tp = tags[b * SS + s - 1];
            num += (float)mk * (trans[tp * TT + tg] + em[s * TT + tg]);
        }
    }
#pragma unroll
    for (int o = 32; o > 0; o >>= 1) {
        num += __shfl_xor(num, o, 64);
        msum += __shfl_xor(msum, o, 64);
    }
    if (lane == 0) { red[wid] = num; redm[wid] = (float)msum; }
    __syncthreads();

    // ---- tree reduction: levels n = 32,16,8,4,2,1, append-buffer ----
    int inOff = 0, outOff = 64;
    for (int n = 32; n >= 1; n >>= 1) {
        for (int c = wid; c < n; c += 4) {
            const float* A  = mats + (inOff + 2 * c) * 81;
            const float* Bm = mats + (inOff + 2 * c + 1) * 81;
            float* C = mats + (outOff + c) * 81;
            int e = lane;                       // entries 0..63
            int ii = e / 9, jj = e - ii * 9;
            float a = 0.0f;
#pragma unroll
            for (int k = 0; k < TT; ++k) a += A[ii * 9 + k] * Bm[k * 9 + jj];
            C[e] = a;
            if (lane < 17) {                    // entries 64..80
                e = 64 + lane; ii = e / 9; jj = e - ii * 9;
                float a2 = 0.0f;
#pragma unroll
                for (int k = 0; k < TT; ++k) a2 += A[ii * 9 + k] * Bm[k * 9 + jj];
                C[e] = a2;
            }
        }
        __syncthreads();
        inOff = outOff; outOff += n;
    }
    // Mtot at mats + 126*81

    if (wid == 0) {
        const float* Mt = mats + 126 * 81;
        float v0[TT];
#pragma unroll
        for (int i2 = 0; i2 < TT; ++i2) v0[i2] = __expf(start_t[i2] + em[i2]);
        const int j = (lane < TT) ? lane : 0;
        float cs = 0.0f;
#pragma unroll
        for (int i2 = 0; i2 < TT; ++i2) cs += v0[i2] * Mt[i2 * 9 + j];
        float val = cs * __expf(end_t[j]);
        if (lane >= TT) val = 0.0f;
        // sum lanes 0..8 (lanes 9..15 are zero) via width-16 butterfly
#pragma unroll
        for (int o = 8; o > 0; o >>= 1) val += __shfl_xor(val, o, 64);
        if (lane == 0) {
            const float den = __logf(val);
            float numT = red[0] + red[1] + red[2] + red[3];
            const int ms = (int)(redm[0] + redm[1] + redm[2] + redm[3]);
            numT += end_t[tags[b * SS + (ms - 1)]];
            atomicAdd(out, numT - den);
        }
    }
}

extern "C" void kernel_launch(void* const* d_in, const int* in_sizes, int n_in,
                              void* d_out, int out_size, void* d_ws, size_t ws_size,
                              hipStream_t stream) {
    const float* embed   = (const float*)d_in[0];
    const int*   tags    = (const int*)d_in[1];
    const int*   mask    = (const int*)d_in[2];
    const float* W       = (const float*)d_in[3];
    const float* bias    = (const float*)d_in[4];
    const float* start_t = (const float*)d_in[5];
    const float* end_t   = (const float*)d_in[6];
    const float* trans   = (const float*)d_in[7];
    float* out = (float*)d_out;
    float* ws  = (float*)d_ws;   // needs 4096*81*4 = 1.33 MB

    // 32768 rows / 64 rows per block (4 waves x 16-row MFMA tile)
    emis_kernel<<<512, 256, 0, stream>>>(embed, W, bias, out);
    // 4096 chunk-waves / 4 waves per block
    crf_chunk<<<1024, 256, 0, stream>>>(out, mask, trans, ws);
    // one block per batch
    crf_final<<<BB, 256, 0, stream>>>(out, tags, mask, start_t, end_t, trans, ws, out);
}